// Round 1
// 195.123 us; speedup vs baseline: 1.0857x; 1.0857x over previous
//
#include <hip/hip_runtime.h>

typedef short short8 __attribute__((ext_vector_type(8)));
typedef float f32x4  __attribute__((ext_vector_type(4)));

constexpr int M_TOT  = 8 * 4096;   // 32768 pixels
constexpr int K_PROT = 1024;
constexpr int D_DIM  = 128;

// ws layout: xsq @0 (128 KB), psq @128K (4 KB), pfrag @132K (512 KB)
constexpr size_t WS_PSQ_OFF = (size_t)M_TOT * 4;
constexpr size_t WS_PF_OFF  = WS_PSQ_OFF + (size_t)K_PROT * 4;

__device__ inline unsigned short bf16_hi(float f) {
  unsigned u = __builtin_bit_cast(unsigned, f);
  unsigned r = u + 0x7FFFu + ((u >> 16) & 1u);   // RNE
  return (unsigned short)(r >> 16);
}
__device__ inline float bf16_tof(unsigned short h) {
  return __builtin_bit_cast(float, (unsigned)h << 16);
}

// LDS-only barrier: ds ops complete (lgkmcnt), but do NOT drain in-flight
// global nontemporal stores (vmcnt) like __syncthreads() would.
__device__ inline void barrier_lds() {
  asm volatile("s_waitcnt lgkmcnt(0)\n\ts_barrier" ::: "memory");
}

// ---------------------------------------------------------------------------
// Row squared-norms for x and p (fp32, exact) -> ws
__global__ __launch_bounds__(256) void norms_kernel(
    const float* __restrict__ x, const float* __restrict__ p,
    float* __restrict__ xsq, float* __restrict__ psq) {
  int group = blockIdx.x * (blockDim.x >> 5) + (threadIdx.x >> 5);
  int lane  = threadIdx.x & 31;
  if (group >= M_TOT + K_PROT) return;
  const float* row = (group < M_TOT) ? (x + (size_t)group * D_DIM)
                                     : (p + (size_t)(group - M_TOT) * D_DIM);
  float4 v = reinterpret_cast<const float4*>(row)[lane];
  float s = v.x * v.x + v.y * v.y + v.z * v.z + v.w * v.w;
  #pragma unroll
  for (int off = 16; off > 0; off >>= 1) s += __shfl_down(s, off, 32);
  if (lane == 0) {
    if (group < M_TOT) xsq[group] = s;
    else psq[group - M_TOT] = s;
  }
}

// ---------------------------------------------------------------------------
// Pre-swizzle protos into MFMA A-fragment order, bf16 hi/lo split.
// g in [0,32768): ng=g>>9 (16-proto group), slot=(g>>6)&7 (part*4+ks), lane=g&63.
// Element: proto = ng*16 + (lane&15), k = ks*32 + (lane>>4)*8 + j.
// Grid MUST be 32768/256 = 128 blocks.
__global__ __launch_bounds__(256) void pfrag_kernel(
    const float* __restrict__ p, short* __restrict__ pf) {
  int g    = blockIdx.x * 256 + threadIdx.x;
  int lane = g & 63;
  int s    = (g >> 6) & 7;
  int ng   = g >> 9;
  int part = s >> 2, ks = s & 3;
  int proto = ng * 16 + (lane & 15);
  int k0    = ks * 32 + (lane >> 4) * 8;
  const float4* pr = (const float4*)(p + (size_t)proto * D_DIM + k0);
  float4 a = pr[0], b = pr[1];
  float e[8] = {a.x, a.y, a.z, a.w, b.x, b.y, b.z, b.w};
  short8 frag;
  #pragma unroll
  for (int j = 0; j < 8; ++j) {
    unsigned short h = bf16_hi(e[j]);
    if (part) h = bf16_hi(e[j] - bf16_tof(h));
    frag[j] = (short)h;
  }
  *(short8*)(pf + (size_t)g * 8) = frag;
}

// ---------------------------------------------------------------------------
// Main: A=protos (global frags, L2-hot), B=pixels (LDS frags). Block = 64 pix,
// 4 waves; wave w covers protos [chunk*256 + w*64, +64) over 4 chunks.
// C/D: col(lane&15)=pixel, row=(lane>>4)*4+reg = 4 consecutive protos.
// NEW: score stores go through a 64x132 fp32 LDS staging buffer in two
// half-chunk rounds so every global store instr is a 512B contiguous run
// (32 lanes/row) instead of 16 scattered 64B segments at 4KB stride.
__global__ __launch_bounds__(256, 2) void proto_mfma(
    const float* __restrict__ x, const float* __restrict__ p,
    const short* __restrict__ pf, const float* __restrict__ xsq,
    const float* __restrict__ psq,
    float* __restrict__ matched, float* __restrict__ scores) {
  __shared__ short xlds[32 * 64 * 8];   // 32 KB: [part*16 + nt*4 + ks][lane][8]
  __shared__ float sbuf[64][132];       // 33.8 KB score staging (pad 4 -> 2-way banks)
  __shared__ float sv[4][64];
  __shared__ int   si[4][64];
  __shared__ int   fidx[64];

  const int tid = threadIdx.x;
  const int w   = tid >> 6;
  const int l   = tid & 63;
  const int m0  = blockIdx.x * 64;

  // ---- stage x tile into LDS in B-fragment order, hi/lo split (once) ----
  #pragma unroll
  for (int i = 0; i < 8; ++i) {
    int piece = i * 256 + tid;          // 0..2047
    int lane = piece & 63;
    int s = piece >> 6;                 // 0..31
    int ks = s & 3, nt = (s >> 2) & 3, part = s >> 4;
    int pix = m0 + nt * 16 + (lane & 15);
    int k0  = ks * 32 + (lane >> 4) * 8;
    const float4* xr = (const float4*)(x + (size_t)pix * D_DIM + k0);
    float4 a = xr[0], b = xr[1];
    float e[8] = {a.x, a.y, a.z, a.w, b.x, b.y, b.z, b.w};
    short8 frag;
    #pragma unroll
    for (int j = 0; j < 8; ++j) {
      unsigned short h = bf16_hi(e[j]);
      if (part) h = bf16_hi(e[j] - bf16_tof(h));
      frag[j] = (short)h;
    }
    *(short8*)(xlds + (size_t)piece * 8) = frag;
  }
  __syncthreads();

  float xs[4];
  #pragma unroll
  for (int nt = 0; nt < 4; ++nt) xs[nt] = xsq[m0 + nt * 16 + (l & 15)];

  float best[4]; int bidx[4];
  #pragma unroll
  for (int nt = 0; nt < 4; ++nt) { best[nt] = -3.4e38f; bidx[nt] = 0; }

  for (int chunk = 0; chunk < 4; ++chunk) {
    f32x4 acc[4][4];
    #pragma unroll
    for (int mt = 0; mt < 4; ++mt)
      #pragma unroll
      for (int nt = 0; nt < 4; ++nt) acc[mt][nt] = (f32x4){0.f, 0.f, 0.f, 0.f};

    const int pgbase = chunk * 16 + w * 4;

    #pragma unroll
    for (int ks = 0; ks < 4; ++ks) {
      short8 pah[4], pal[4], bh[4], bl[4];
      #pragma unroll
      for (int mt = 0; mt < 4; ++mt) {
        pah[mt] = *(const short8*)(pf + ((size_t)((pgbase + mt) * 8 + ks) * 64 + l) * 8);
        pal[mt] = *(const short8*)(pf + ((size_t)((pgbase + mt) * 8 + 4 + ks) * 64 + l) * 8);
      }
      #pragma unroll
      for (int nt = 0; nt < 4; ++nt) {
        bh[nt] = *(const short8*)(xlds + (size_t)(((nt * 4 + ks) * 64) + l) * 8);
        bl[nt] = *(const short8*)(xlds + (size_t)(((16 + nt * 4 + ks) * 64) + l) * 8);
      }
      #pragma unroll
      for (int mt = 0; mt < 4; ++mt)
        #pragma unroll
        for (int nt = 0; nt < 4; ++nt)
          acc[mt][nt] = __builtin_amdgcn_mfma_f32_16x16x32_bf16(pah[mt], bh[nt], acc[mt][nt], 0, 0, 0);
      #pragma unroll
      for (int mt = 0; mt < 4; ++mt)
        #pragma unroll
        for (int nt = 0; nt < 4; ++nt)
          acc[mt][nt] = __builtin_amdgcn_mfma_f32_16x16x32_bf16(pah[mt], bl[nt], acc[mt][nt], 0, 0, 0);
      #pragma unroll
      for (int mt = 0; mt < 4; ++mt)
        #pragma unroll
        for (int nt = 0; nt < 4; ++nt)
          acc[mt][nt] = __builtin_amdgcn_mfma_f32_16x16x32_bf16(pal[mt], bh[nt], acc[mt][nt], 0, 0, 0);
    }

    // ---- transform acc in place to final score values + running argmax ----
    #pragma unroll
    for (int mt = 0; mt < 4; ++mt) {
      int pbase = chunk * 256 + w * 64 + mt * 16 + (l >> 4) * 4;
      float psa[4];
      *(float4*)psa = *(const float4*)(psq + pbase);
      #pragma unroll
      for (int nt = 0; nt < 4; ++nt) {
        f32x4 o;
        {
          #pragma clang fp contract(off)
          #pragma unroll
          for (int r = 0; r < 4; ++r) {
            float t = (xs[nt] + psa[r]) - 2.0f * acc[mt][nt][r];
            o[r] = -t;
            if (o[r] > best[nt]) { best[nt] = o[r]; bidx[nt] = pbase + r; }
          }
        }
        acc[mt][nt] = o;   // acc now holds final scores
      }
    }

    // ---- two staging+store rounds: waves {2h,2h+1} stage cols [h*128,+128) ----
    #pragma unroll
    for (int h = 0; h < 2; ++h) {
      if ((w >> 1) == h) {
        const int colbase = (w & 1) * 64 + (l >> 4) * 4;
        #pragma unroll
        for (int mt = 0; mt < 4; ++mt)
          #pragma unroll
          for (int nt = 0; nt < 4; ++nt)
            *(f32x4*)&sbuf[nt * 16 + (l & 15)][colbase + mt * 16] = acc[mt][nt];
      }
      barrier_lds();
      const int gbase = chunk * 256 + h * 128;
      #pragma unroll
      for (int ps = 0; ps < 8; ++ps) {
        int idx = ps * 256 + tid;
        int row = idx >> 5;          // 0..63 (8 rows per pass)
        int f4  = idx & 31;          // 0..31 (128 cols / 4)
        f32x4 v = *(const f32x4*)&sbuf[row][f4 * 4];
        __builtin_nontemporal_store(v,
            (f32x4*)(scores + (size_t)(m0 + row) * K_PROT + gbase + f4 * 4));
      }
      barrier_lds();   // readers done before next round's writers overwrite sbuf
    }
  }

  // ---- argmax reduce: butterfly over quads, then LDS over waves ----
  #pragma unroll
  for (int nt = 0; nt < 4; ++nt) {
    #pragma unroll
    for (int m = 16; m <= 32; m <<= 1) {
      float ov = __shfl_xor(best[nt], m);
      int   oi = __shfl_xor(bidx[nt], m);
      if (ov > best[nt] || (ov == best[nt] && oi < bidx[nt])) {
        best[nt] = ov; bidx[nt] = oi;
      }
    }
  }
  if (l < 16) {
    #pragma unroll
    for (int nt = 0; nt < 4; ++nt) {
      sv[w][nt * 16 + l] = best[nt];
      si[w][nt * 16 + l] = bidx[nt];
    }
  }
  __syncthreads();
  if (tid < 64) {
    float v = sv[0][tid]; int bi = si[0][tid];
    #pragma unroll
    for (int e = 1; e < 4; ++e) {
      float vv = sv[e][tid]; int ii = si[e][tid];
      if (vv > v || (vv == v && ii < bi)) { v = vv; bi = ii; }
    }
    fidx[tid] = bi;
  }
  __syncthreads();

  // ---- gather matched = original fp32 prototypes[argmax] ----
  for (int q = tid; q < 64 * 32; q += 256) {
    int pix = q >> 5, f4 = q & 31;
    float4 v = ((const float4*)(p + (size_t)fidx[pix] * D_DIM))[f4];
    __builtin_nontemporal_store(*(f32x4*)&v,
        (f32x4*)(matched + (size_t)(m0 + pix) * D_DIM) + f4);
  }
}

// ---------------------------------------------------------------------------
extern "C" void kernel_launch(void* const* d_in, const int* in_sizes, int n_in,
                              void* d_out, int out_size, void* d_ws, size_t ws_size,
                              hipStream_t stream) {
  const float* x = (const float*)d_in[0];   // [B,N,D] fp32
  const float* p = (const float*)d_in[1];   // [K,D]   fp32

  float* matched = (float*)d_out;                            // [B,N,D]
  float* scores  = (float*)d_out + (size_t)M_TOT * D_DIM;    // [B,N,K]

  float* xsq = (float*)d_ws;
  float* psq = (float*)((char*)d_ws + WS_PSQ_OFF);
  short* pf  = (short*)((char*)d_ws + WS_PF_OFF);

  {
    int rows = M_TOT + K_PROT;
    int blocks = (rows + 7) / 8;
    norms_kernel<<<blocks, 256, 0, stream>>>(x, p, xsq, psq);
  }
  pfrag_kernel<<<128, 256, 0, stream>>>(p, pf);              // 32768 frags / 256
  proto_mfma<<<M_TOT / 64, 256, 0, stream>>>(x, p, pf, xsq, psq, matched, scores);
}